// Round 1
// 536.309 us; speedup vs baseline: 1.0162x; 1.0162x over previous
//
#include <hip/hip_runtime.h>
#include <hip/hip_bf16.h>

// StratifiedRaysampler on MI355X — v3: fat grid-stride blocks, ILP unroll.
//
// d_out layout (flat): sample_points [262144,128,3] fp32, then
// sample_lengths [262144,128,1] fp32.  Total 33,554,432 float4s = 512 MiB.
// Pure write-BW bound (~3 MiB of real input reads).
//
// v2 mapped 1 thread -> 1 output float4 (131,072 tiny blocks).  rocprof
// showed the harness fill streaming at 6.3 TB/s while the kernel ran at
// ~2.6 TB/s: each v2 wave issued one 1 KiB store gated behind a dependent
// 3-load chain, then the block retired — store pipe idles on block churn.
//
// v3: 2048 blocks (8/CU — full occupancy), each block owns 16,384
// CONSECUTIVE float4s (256 KiB span, good DRAM page locality).  Thread t
// writes float4s t, t+256, t+512, ... within the chunk: every wave-store
// remains one contiguous 1 KiB burst, and each thread has 64 independent
// store iterations (unroll 4 -> 4 loads+stores in flight).  Per-ray dirs
// reads stay L1-broadcast-hot (a block's chunk covers ~171 rays = 2 KB).
//
// Per-element math is IDENTICAL to v2 (passed absmax there):
// points[i,j,:] = (z_j*rx, z_j*ry, z_j) with rx=dx/dz, ry=dy/dz.
// float4 #r of a ray (96/ray, no straddle) has phase e = r%3:
//   e==0: (x_j, y_j, z_j, x_{j+1})
//   e==1: (y_j, z_j, x_{j+1}, y_{j+1})
//   e==2: (z_j, x_{j+1}, y_{j+1}, z_{j+1})     with j = 4r/3.
// lengths float4 = (z_k .. z_{k+3}), k = (idx%32)*4 — no loads.

constexpr int      kNPts    = 128;
constexpr int      kNRays   = 262144;
constexpr float    kMinD    = 0.1f;
constexpr float    kMaxD    = 6.0f;
constexpr float    kStep    = (kMaxD - kMinD) / (float)(kNPts - 1);
constexpr unsigned kPtsF4   = (unsigned)kNRays * kNPts * 3 / 4;  // 25,165,824
constexpr unsigned kTotalF4 = (unsigned)kNRays * kNPts * 4 / 4;  // 33,554,432
constexpr unsigned kChunk   = 16384;                             // float4s per block
constexpr unsigned kBlocks  = kTotalF4 / kChunk;                 // 2048 blocks

__global__ __launch_bounds__(256) void StratifiedRaysampler_kernel(
    const float* __restrict__ dirs,   // [N_RAYS,3]
    float4* __restrict__ out)         // points then lengths, as float4
{
    const unsigned base = blockIdx.x * kChunk;

#pragma unroll 4
    for (unsigned i = threadIdx.x; i < kChunk; i += 256u) {
        const unsigned u = base + i;
        float4 v;

        if (u < kPtsF4) {
            // ---- points region ----
            const unsigned ray = u / 96u;            // magic-mul div
            const unsigned r   = u - ray * 96u;
            const unsigned f0  = r * 4u;
            const unsigned j   = f0 / 3u;            // const-div
            const unsigned e   = f0 - j * 3u;

            // neighbors share a ray -> L1-broadcast-cheap loads
            const float dx = dirs[ray * 3u + 0u];
            const float dy = dirs[ray * 3u + 1u];
            const float dz = dirs[ray * 3u + 2u];
            const float inv = 1.0f / dz;
            const float rx = dx * inv;
            const float ry = dy * inv;

            const float z0 = kMinD + (float)j * kStep;
            const float z1 = z0 + kStep;

            if (e == 0u)      v = make_float4(z0 * rx, z0 * ry, z0,      z1 * rx);
            else if (e == 1u) v = make_float4(z0 * ry, z0,      z1 * rx, z1 * ry);
            else              v = make_float4(z0,      z1 * rx, z1 * ry, z1);
        } else {
            // ---- lengths region: value depends only on point index ----
            const unsigned v4 = u - kPtsF4;
            const unsigned k  = (v4 & 31u) * 4u;     // 32 float4s per ray
            const float z0 = kMinD + (float)k * kStep;
            v = make_float4(z0, z0 + kStep, z0 + 2.0f * kStep, z0 + 3.0f * kStep);
        }
        out[u] = v;
    }
}

extern "C" void kernel_launch(void* const* d_in, const int* in_sizes, int n_in,
                              void* d_out, int out_size, void* d_ws, size_t ws_size,
                              hipStream_t stream) {
    // d_in[0] = origins (unused by the reference math), d_in[1] = directions
    const float* dirs = (const float*)d_in[1];
    float4* out = (float4*)d_out;

    StratifiedRaysampler_kernel<<<kBlocks, 256, 0, stream>>>(dirs, out);
}